// Round 9
// baseline (121.739 us; speedup 1.0000x reference)
//
#include <hip/hip_runtime.h>
#include <hip/hip_bf16.h>

// ALiBi attention, B=8 L=1024 H=8 E=64, fp32 in/out, bf16 MFMA inside.
// Outputs: V [B,L,H,E] then series [B,H,L,L] concatenated in d_out.
// R9 = R8 + (a) 32 q-rows per wave (2 Q-frags; halves LDS reads per score)
//         + (b) double-buffered 2-phase staging pipeline (1 barrier/chunk).
// Scratch: bf16 K and V^T chunks pre-swizzled in gload-linear order.

typedef short short8 __attribute__((ext_vector_type(8)));
typedef short short4v __attribute__((ext_vector_type(4)));
typedef float f32x4 __attribute__((ext_vector_type(4)));
typedef unsigned short u16x4 __attribute__((ext_vector_type(4)));

#define B_ 8
#define L_ 1024
#define H_ 8
#define E_ 64
#define RSTRIDE (H_ * E_)       // 512 floats between seq rows
#define QBLK 128                // 4 waves x 32 q-rows
#define CHUNK 64                // keys per chunk
#define NCH (L_ / CHUNK)        // 16
#define CHUNK_USH (CHUNK * E_)  // 4096 ushorts = 8KB per chunk tile

__device__ __forceinline__ unsigned short f2bf(float f) {
  return __builtin_bit_cast(unsigned short, __float2bfloat16(f));
}
__device__ __forceinline__ short8 ldfrag(const float* p) {
  float4 a = *reinterpret_cast<const float4*>(p);
  float4 b = *reinterpret_cast<const float4*>(p + 4);
  return (short8){(short)f2bf(a.x), (short)f2bf(a.y), (short)f2bf(a.z),
                  (short)f2bf(a.w), (short)f2bf(b.x), (short)f2bf(b.y),
                  (short)f2bf(b.z), (short)f2bf(b.w)};
}

__device__ __forceinline__ f32x4 mfma16(short4v a, short4v b, f32x4 c) {
#if __has_builtin(__builtin_amdgcn_mfma_f32_16x16x16bf16_1k)
  return __builtin_amdgcn_mfma_f32_16x16x16bf16_1k(a, b, c, 0, 0, 0);
#else
  asm volatile(
      "s_nop 1\n\t"
      "v_mfma_f32_16x16x16_bf16 %0, %1, %2, %0\n\t"
      "s_nop 2"
      : "+v"(c)
      : "v"(a), "v"(b));
  return c;
#endif
}

__device__ __forceinline__ void gld16(const unsigned short* g,
                                      unsigned short* l) {
  __builtin_amdgcn_global_load_lds(
      (const __attribute__((address_space(1))) unsigned int*)g,
      (__attribute__((address_space(3))) unsigned int*)l, 16, 0, 0);
}

// ---- prep: scratch in gload-linear swizzled block order ----
// K chunk (64 s x 64 e): 16B-block j <-> (s = j>>3, e8 = (j&7)^(s&7)).
// VT chunk (64 e x 64 s): block j <-> (e = j>>4? no: e = j>>3, g = (j&7)^(e&7)).
__global__ __launch_bounds__(256, 4) void prep_kv(
    const float* __restrict__ Kg, const float* __restrict__ Vg,
    unsigned short* __restrict__ Kbf, unsigned short* __restrict__ VTbf) {
  __shared__ unsigned short vt[64 * 64];  // V^T tile in swizzled space

  const int t = threadIdx.x;
  const int id = blockIdx.x;
  const int bh = id & 63;  // id%8 = h -> same XCD as consumers
  const int sc = id >> 6;  // chunk 0..15
  const int h = bh & 7, b = bh >> 3;
  const int s0 = sc * CHUNK;

  const float* Kb = Kg + ((size_t)b * L_ + s0) * RSTRIDE + h * E_;
  const float* Vb = Vg + ((size_t)b * L_ + s0) * RSTRIDE + h * E_;
  unsigned short* Ko = Kbf + (size_t)(bh * NCH + sc) * CHUNK_USH;
  unsigned short* Vo = VTbf + (size_t)(bh * NCH + sc) * CHUNK_USH;

  // K: direct convert into swizzled block order (reads stay coalesced)
#pragma unroll
  for (int i = 0; i < 2; ++i) {
    const int j = t + 256 * i;  // 512 blocks
    const int s = j >> 3;
    const int e8 = (j & 7) ^ (s & 7);
    const float* kp = Kb + (size_t)s * RSTRIDE + 8 * e8;
    float4 a = *reinterpret_cast<const float4*>(kp);
    float4 c = *reinterpret_cast<const float4*>(kp + 4);
    *reinterpret_cast<u16x4*>(&Ko[j * 8]) =
        (u16x4){f2bf(a.x), f2bf(a.y), f2bf(a.z), f2bf(a.w)};
    *reinterpret_cast<u16x4*>(&Ko[j * 8 + 4]) =
        (u16x4){f2bf(c.x), f2bf(c.y), f2bf(c.z), f2bf(c.w)};
  }
  // V: transpose through LDS (swizzled space), then linear copy out
  {
    const int e = t & 63, w = t >> 6;
#pragma unroll
    for (int i = 0; i < 4; ++i) {
      const int s4 = 4 * w + 16 * i;
      const float* vp = Vb + (size_t)s4 * RSTRIDE + e;
      u16x4 u = {f2bf(vp[0]), f2bf(vp[RSTRIDE]), f2bf(vp[2 * RSTRIDE]),
                 f2bf(vp[3 * RSTRIDE])};
      *reinterpret_cast<u16x4*>(
          &vt[e * 64 + (((s4 >> 3) ^ (e & 7)) << 3) + (s4 & 7)]) = u;
    }
  }
  __syncthreads();
#pragma unroll
  for (int i = 0; i < 2; ++i) {
    const int j = t + 256 * i;  // swizzled space is already block-linear
    u16x4 u0 = *reinterpret_cast<const u16x4*>(&vt[j * 8]);
    u16x4 u1 = *reinterpret_cast<const u16x4*>(&vt[j * 8 + 4]);
    *reinterpret_cast<u16x4*>(&Vo[j * 8]) = u0;
    *reinterpret_cast<u16x4*>(&Vo[j * 8 + 4]) = u1;
  }
}

// ---- main: 4 waves x 32 q-rows, double-buffered staging ----
__global__ __launch_bounds__(256, 2) void alibi_attn(
    const float* __restrict__ Qg, const unsigned short* __restrict__ Kbf,
    const unsigned short* __restrict__ VTbf, float* __restrict__ Vout,
    float* __restrict__ Pout) {
  __shared__ unsigned short sK[2][CHUNK_USH];   // 8KB each, swizzled [s][e]
  __shared__ unsigned short sVT[2][CHUNK_USH];  // 8KB each, swizzled [e][s]

  const int t = threadIdx.x;
  const int lane = t & 63;
  const int w = t >> 6;
  const int col = lane & 15;
  const int kg = lane >> 4;

  const int id = blockIdx.x;  // id%8 = h -> XCD-pinned scratch in L2
  const int qb = id >> 6;
  const int bh = id & 63;
  const int h = bh & 7;
  const int b = bh >> 3;
  const int q0 = qb * QBLK;

  const float sc_l2e = 0.125f * 1.44269504f;
  const float sl_l2e = exp2f(-(float)(h + 1) * 0.125f) * 1.44269504f;

  const unsigned short* Kc = Kbf + (size_t)bh * NCH * CHUNK_USH;
  const unsigned short* Vc = VTbf + (size_t)bh * NCH * CHUNK_USH;

  // two Q B-fragment sets: rows qA = q0+32w+col, qB = qA+16
  short8 qfA0, qfA1, qfB0, qfB1;
  {
    const float* qp =
        Qg + ((size_t)b * L_ + q0 + 32 * w + col) * RSTRIDE + h * E_ + 8 * kg;
    qfA0 = ldfrag(qp);
    qfA1 = ldfrag(qp + 32);
    qfB0 = ldfrag(qp + 16 * RSTRIDE);
    qfB1 = ldfrag(qp + 16 * RSTRIDE + 32);
  }

  const float kbias0 = sl_l2e * (float)(4 * kg - 1023) - 32.0f;

#define STAGE_K(c, bi)                                                    \
  {                                                                       \
    const unsigned short* src = Kc + (size_t)(c) * CHUNK_USH;             \
    _Pragma("unroll") for (int i = 0; i < 2; ++i) {                       \
      const int seg = i * 4 + w;                                          \
      gld16(src + (size_t)(seg * 64 + lane) * 8, &sK[bi][seg * 512]);     \
    }                                                                     \
  }
#define STAGE_V(c, bi)                                                    \
  {                                                                       \
    const unsigned short* src = Vc + (size_t)(c) * CHUNK_USH;             \
    _Pragma("unroll") for (int i = 0; i < 2; ++i) {                       \
      const int seg = i * 4 + w;                                          \
      gld16(src + (size_t)(seg * 64 + lane) * 8, &sVT[bi][seg * 512]);    \
    }                                                                     \
  }

  // ===== Pass A: z = sum exp2(u-32), pipelined K staging =====
  float zA = 0.f, zB = 0.f;
  STAGE_K(0, 0);
  __syncthreads();
  for (int c = 0; c < NCH; ++c) {
    if (c + 1 < NCH) STAGE_K(c + 1, (c + 1) & 1);
    const unsigned short* kb = sK[c & 1];
#pragma unroll
    for (int kt = 0; kt < 4; ++kt) {
      const int row = 16 * kt + col;
      short8 k0 = *reinterpret_cast<const short8*>(
          &kb[row * 64 + ((kg ^ (row & 7)) << 3)]);
      short8 k1 = *reinterpret_cast<const short8*>(
          &kb[row * 64 + (((kg + 4) ^ (row & 7)) << 3)]);
      f32x4 aA = {0.f, 0.f, 0.f, 0.f}, aB = {0.f, 0.f, 0.f, 0.f};
      aA = __builtin_amdgcn_mfma_f32_16x16x32_bf16(k0, qfA0, aA, 0, 0, 0);
      aA = __builtin_amdgcn_mfma_f32_16x16x32_bf16(k1, qfA1, aA, 0, 0, 0);
      aB = __builtin_amdgcn_mfma_f32_16x16x32_bf16(k0, qfB0, aB, 0, 0, 0);
      aB = __builtin_amdgcn_mfma_f32_16x16x32_bf16(k1, qfB1, aB, 0, 0, 0);
      const float base = fmaf((float)(CHUNK * c + 16 * kt), sl_l2e, kbias0);
#pragma unroll
      for (int r = 0; r < 4; ++r) {
        const float bb = base + (float)r * sl_l2e;
        zA += __builtin_amdgcn_exp2f(fmaf(aA[r], sc_l2e, bb));
        zB += __builtin_amdgcn_exp2f(fmaf(aB[r], sc_l2e, bb));
      }
    }
    __syncthreads();
  }
  zA += __shfl_xor(zA, 16, 64);
  zA += __shfl_xor(zA, 32, 64);
  zB += __shfl_xor(zB, 16, 64);
  zB += __shfl_xor(zB, 32, 64);
  const float minvA = 1.0f / zA;
  const float minvB = 1.0f / zB;

  // ===== Pass B =====
  f32x4 oA[4], oB[4];
#pragma unroll
  for (int et = 0; et < 4; ++et) {
    oA[et] = (f32x4){0.f, 0.f, 0.f, 0.f};
    oB[et] = (f32x4){0.f, 0.f, 0.f, 0.f};
  }

  float* PbA = Pout + ((size_t)(b * H_ + h) * L_ + q0 + 32 * w + col) * L_ +
               4 * kg;
  float* PbB = PbA + (size_t)16 * L_;

  STAGE_K(0, 0);
  STAGE_V(0, 0);
  __syncthreads();
  for (int c = 0; c < NCH; ++c) {
    if (c + 1 < NCH) {
      STAGE_K(c + 1, (c + 1) & 1);
      STAGE_V(c + 1, (c + 1) & 1);
    }
    const unsigned short* kb = sK[c & 1];
    const unsigned short* vb = sVT[c & 1];
#pragma unroll
    for (int kt = 0; kt < 4; ++kt) {
      const int row = 16 * kt + col;
      short8 k0 = *reinterpret_cast<const short8*>(
          &kb[row * 64 + ((kg ^ (row & 7)) << 3)]);
      short8 k1 = *reinterpret_cast<const short8*>(
          &kb[row * 64 + (((kg + 4) ^ (row & 7)) << 3)]);
      f32x4 aA = {0.f, 0.f, 0.f, 0.f}, aB = {0.f, 0.f, 0.f, 0.f};
      aA = __builtin_amdgcn_mfma_f32_16x16x32_bf16(k0, qfA0, aA, 0, 0, 0);
      aA = __builtin_amdgcn_mfma_f32_16x16x32_bf16(k1, qfA1, aA, 0, 0, 0);
      aB = __builtin_amdgcn_mfma_f32_16x16x32_bf16(k0, qfB0, aB, 0, 0, 0);
      aB = __builtin_amdgcn_mfma_f32_16x16x32_bf16(k1, qfB1, aB, 0, 0, 0);
      // V^T fragments, shared by both q-sets
      short4v vf[4];
      const int g0 = 2 * kt + (kg >> 1);
      const int so = 4 * (kg & 1);
#pragma unroll
      for (int et = 0; et < 4; ++et) {
        const int e = 16 * et + col;
        vf[et] = *reinterpret_cast<const short4v*>(
            &vb[e * 64 + ((g0 ^ (e & 7)) << 3) + so]);
      }
      const float base = fmaf((float)(CHUNK * c + 16 * kt), sl_l2e, kbias0);
      f32x4 pA, pB;
#pragma unroll
      for (int r = 0; r < 4; ++r) {
        const float bb = base + (float)r * sl_l2e;
        pA[r] = __builtin_amdgcn_exp2f(fmaf(aA[r], sc_l2e, bb)) * minvA;
        pB[r] = __builtin_amdgcn_exp2f(fmaf(aB[r], sc_l2e, bb)) * minvB;
      }
      *reinterpret_cast<f32x4*>(PbA + CHUNK * c + 16 * kt) = pA;
      *reinterpret_cast<f32x4*>(PbB + CHUNK * c + 16 * kt) = pB;
      short4v paA = {(short)f2bf(pA[0]), (short)f2bf(pA[1]),
                     (short)f2bf(pA[2]), (short)f2bf(pA[3])};
      short4v paB = {(short)f2bf(pB[0]), (short)f2bf(pB[1]),
                     (short)f2bf(pB[2]), (short)f2bf(pB[3])};
#pragma unroll
      for (int et = 0; et < 4; ++et) {
        oA[et] = mfma16(paA, vf[et], oA[et]);
        oB[et] = mfma16(paB, vf[et], oB[et]);
      }
    }
    __syncthreads();
  }

  // ---- write O: qA = q0+32w+4kg+r, qB = +16; e = 16et+col ----
  float* VoA = Vout + (((size_t)b * L_ + q0 + 32 * w) * H_ + h) * E_;
  float* VoB = VoA + (size_t)16 * RSTRIDE;
#pragma unroll
  for (int et = 0; et < 4; ++et) {
#pragma unroll
    for (int r = 0; r < 4; ++r) {
      __builtin_nontemporal_store(oA[et][r],
                                  &VoA[(4 * kg + r) * RSTRIDE + 16 * et + col]);
      __builtin_nontemporal_store(oB[et][r],
                                  &VoB[(4 * kg + r) * RSTRIDE + 16 * et + col]);
    }
  }
}

extern "C" void kernel_launch(void* const* d_in, const int* in_sizes, int n_in,
                              void* d_out, int out_size, void* d_ws,
                              size_t ws_size, hipStream_t stream) {
  const float* Q = (const float*)d_in[0];
  const float* K = (const float*)d_in[1];
  const float* V = (const float*)d_in[2];
  float* out = (float*)d_out;
  float* Vo = out;                              // [B,L,H,E]
  float* Po = out + (size_t)B_ * L_ * H_ * E_;  // [B,H,L,L]
  unsigned short* Kbf = (unsigned short*)d_ws;  // 8 MB
  unsigned short* VTbf = Kbf + (size_t)B_ * H_ * L_ * E_;  // 8 MB
  hipLaunchKernelGGL(prep_kv, dim3(NCH * B_ * H_), dim3(256), 0, stream, K, V,
                     Kbf, VTbf);
  hipLaunchKernelGGL(alibi_attn, dim3((L_ / QBLK) * H_ * B_), dim3(256), 0,
                     stream, Q, Kbf, VTbf, Vo, Po);
}

// Round 10
// 105.490 us; speedup vs baseline: 1.1540x; 1.1540x over previous
//
#include <hip/hip_runtime.h>
#include <hip/hip_bf16.h>

// ALiBi attention, B=8 L=1024 H=8 E=64, fp32 in/out, bf16 MFMA inside.
// Outputs: V [B,L,H,E] then series [B,H,L,L] concatenated in d_out.
// R10 = R8 geometry (QBLK=64, 4 waves x 16 q-rows, grid 1024, 4 blk/CU)
//     + CHUNK=64 double-buffered staging pipeline (issue next chunk's
//       global_load_lds before computing current; 1 barrier per chunk).
// Scratch: bf16 K and V^T chunks pre-swizzled in gload-linear order.

typedef short short8 __attribute__((ext_vector_type(8)));
typedef short short4v __attribute__((ext_vector_type(4)));
typedef float f32x4 __attribute__((ext_vector_type(4)));
typedef unsigned short u16x4 __attribute__((ext_vector_type(4)));

#define B_ 8
#define L_ 1024
#define H_ 8
#define E_ 64
#define RSTRIDE (H_ * E_)       // 512 floats between seq rows
#define QBLK 64                 // 4 waves x 16 q-rows
#define CHUNK 64                // keys per chunk
#define NCH (L_ / CHUNK)        // 16
#define CHUNK_USH (CHUNK * E_)  // 4096 ushorts = 8KB per chunk tile

__device__ __forceinline__ unsigned short f2bf(float f) {
  return __builtin_bit_cast(unsigned short, __float2bfloat16(f));
}
__device__ __forceinline__ short8 ldfrag(const float* p) {
  float4 a = *reinterpret_cast<const float4*>(p);
  float4 b = *reinterpret_cast<const float4*>(p + 4);
  return (short8){(short)f2bf(a.x), (short)f2bf(a.y), (short)f2bf(a.z),
                  (short)f2bf(a.w), (short)f2bf(b.x), (short)f2bf(b.y),
                  (short)f2bf(b.z), (short)f2bf(b.w)};
}

__device__ __forceinline__ f32x4 mfma16(short4v a, short4v b, f32x4 c) {
#if __has_builtin(__builtin_amdgcn_mfma_f32_16x16x16bf16_1k)
  return __builtin_amdgcn_mfma_f32_16x16x16bf16_1k(a, b, c, 0, 0, 0);
#else
  asm volatile(
      "s_nop 1\n\t"
      "v_mfma_f32_16x16x16_bf16 %0, %1, %2, %0\n\t"
      "s_nop 2"
      : "+v"(c)
      : "v"(a), "v"(b));
  return c;
#endif
}

__device__ __forceinline__ void gld16(const unsigned short* g,
                                      unsigned short* l) {
  __builtin_amdgcn_global_load_lds(
      (const __attribute__((address_space(1))) unsigned int*)g,
      (__attribute__((address_space(3))) unsigned int*)l, 16, 0, 0);
}

// ---- prep: scratch in gload-linear swizzled block order ----
// K chunk (64 s x 64 e): 16B-block j <-> (s = j>>3, e8 = (j&7)^(s&7)).
// VT chunk (64 e x 64 s): block j <-> (e = j>>3, g = (j&7)^(e&7)).
__global__ __launch_bounds__(256, 4) void prep_kv(
    const float* __restrict__ Kg, const float* __restrict__ Vg,
    unsigned short* __restrict__ Kbf, unsigned short* __restrict__ VTbf) {
  __shared__ unsigned short vt[64 * 64];  // V^T tile in swizzled space

  const int t = threadIdx.x;
  const int id = blockIdx.x;
  const int bh = id & 63;  // id%8 = h -> same XCD as consumers
  const int sc = id >> 6;  // chunk 0..15
  const int h = bh & 7, b = bh >> 3;
  const int s0 = sc * CHUNK;

  const float* Kb = Kg + ((size_t)b * L_ + s0) * RSTRIDE + h * E_;
  const float* Vb = Vg + ((size_t)b * L_ + s0) * RSTRIDE + h * E_;
  unsigned short* Ko = Kbf + (size_t)(bh * NCH + sc) * CHUNK_USH;
  unsigned short* Vo = VTbf + (size_t)(bh * NCH + sc) * CHUNK_USH;

  // K: direct convert into swizzled block order (reads stay coalesced)
#pragma unroll
  for (int i = 0; i < 2; ++i) {
    const int j = t + 256 * i;  // 512 blocks
    const int s = j >> 3;
    const int e8 = (j & 7) ^ (s & 7);
    const float* kp = Kb + (size_t)s * RSTRIDE + 8 * e8;
    float4 a = *reinterpret_cast<const float4*>(kp);
    float4 c = *reinterpret_cast<const float4*>(kp + 4);
    *reinterpret_cast<u16x4*>(&Ko[j * 8]) =
        (u16x4){f2bf(a.x), f2bf(a.y), f2bf(a.z), f2bf(a.w)};
    *reinterpret_cast<u16x4*>(&Ko[j * 8 + 4]) =
        (u16x4){f2bf(c.x), f2bf(c.y), f2bf(c.z), f2bf(c.w)};
  }
  // V: transpose through LDS (swizzled space), then linear copy out
  {
    const int e = t & 63, w = t >> 6;
#pragma unroll
    for (int i = 0; i < 4; ++i) {
      const int s4 = 4 * w + 16 * i;
      const float* vp = Vb + (size_t)s4 * RSTRIDE + e;
      u16x4 u = {f2bf(vp[0]), f2bf(vp[RSTRIDE]), f2bf(vp[2 * RSTRIDE]),
                 f2bf(vp[3 * RSTRIDE])};
      *reinterpret_cast<u16x4*>(
          &vt[e * 64 + (((s4 >> 3) ^ (e & 7)) << 3) + (s4 & 7)]) = u;
    }
  }
  __syncthreads();
#pragma unroll
  for (int i = 0; i < 2; ++i) {
    const int j = t + 256 * i;  // swizzled space is already block-linear
    u16x4 u0 = *reinterpret_cast<const u16x4*>(&vt[j * 8]);
    u16x4 u1 = *reinterpret_cast<const u16x4*>(&vt[j * 8 + 4]);
    *reinterpret_cast<u16x4*>(&Vo[j * 8]) = u0;
    *reinterpret_cast<u16x4*>(&Vo[j * 8 + 4]) = u1;
  }
}

// ---- main: 4 waves x 16 q-rows, double-buffered pipelined staging ----
__global__ __launch_bounds__(256, 4) void alibi_attn(
    const float* __restrict__ Qg, const unsigned short* __restrict__ Kbf,
    const unsigned short* __restrict__ VTbf, float* __restrict__ Vout,
    float* __restrict__ Pout) {
  __shared__ unsigned short sK[2][CHUNK_USH];   // 8KB each, swizzled [s][e]
  __shared__ unsigned short sVT[2][CHUNK_USH];  // 8KB each, swizzled [e][s]

  const int t = threadIdx.x;
  const int lane = t & 63;
  const int w = t >> 6;
  const int col = lane & 15;
  const int kg = lane >> 4;

  const int id = blockIdx.x;  // id%8 = h -> XCD-pinned scratch in L2
  const int qb = id >> 6;
  const int bh = id & 63;
  const int h = bh & 7;
  const int b = bh >> 3;
  const int q0 = qb * QBLK;

  const float sc_l2e = 0.125f * 1.44269504f;
  const float sl_l2e = exp2f(-(float)(h + 1) * 0.125f) * 1.44269504f;

  const unsigned short* Kc = Kbf + (size_t)bh * NCH * CHUNK_USH;
  const unsigned short* Vc = VTbf + (size_t)bh * NCH * CHUNK_USH;

  // Q B-fragments: q-row = col, k = 8*kg + j (+32 for second slice)
  short8 qf0, qf1;
  {
    const float* qp =
        Qg + ((size_t)b * L_ + q0 + 16 * w + col) * RSTRIDE + h * E_ + 8 * kg;
    qf0 = ldfrag(qp);
    qf1 = ldfrag(qp + 32);
  }

  const float kbias0 = sl_l2e * (float)(4 * kg - 1023) - 32.0f;

#define STAGE_K(c, bi)                                                  \
  {                                                                     \
    const unsigned short* src = Kc + (size_t)(c) * CHUNK_USH;           \
    _Pragma("unroll") for (int i = 0; i < 2; ++i) {                     \
      const int seg = i * 4 + w;                                        \
      gld16(src + (size_t)(seg * 64 + lane) * 8, &sK[bi][seg * 512]);   \
    }                                                                   \
  }
#define STAGE_V(c, bi)                                                  \
  {                                                                     \
    const unsigned short* src = Vc + (size_t)(c) * CHUNK_USH;           \
    _Pragma("unroll") for (int i = 0; i < 2; ++i) {                     \
      const int seg = i * 4 + w;                                        \
      gld16(src + (size_t)(seg * 64 + lane) * 8, &sVT[bi][seg * 512]);  \
    }                                                                   \
  }

  // ===== Pass A: z = sum exp2(u-32), pipelined K staging =====
  float z0 = 0.f, z1 = 0.f, z2 = 0.f, z3 = 0.f;
  STAGE_K(0, 0);
  __syncthreads();
  for (int c = 0; c < NCH; ++c) {
    if (c + 1 < NCH) STAGE_K(c + 1, (c + 1) & 1);
    const unsigned short* kb = sK[c & 1];
#pragma unroll
    for (int kt = 0; kt < 4; ++kt) {
      const int row = 16 * kt + col;
      short8 k0 = *reinterpret_cast<const short8*>(
          &kb[row * 64 + ((kg ^ (row & 7)) << 3)]);
      short8 k1 = *reinterpret_cast<const short8*>(
          &kb[row * 64 + (((kg + 4) ^ (row & 7)) << 3)]);
      f32x4 acc = {0.f, 0.f, 0.f, 0.f};
      acc = __builtin_amdgcn_mfma_f32_16x16x32_bf16(k0, qf0, acc, 0, 0, 0);
      acc = __builtin_amdgcn_mfma_f32_16x16x32_bf16(k1, qf1, acc, 0, 0, 0);
      const float base = fmaf((float)(CHUNK * c + 16 * kt), sl_l2e, kbias0);
      z0 += __builtin_amdgcn_exp2f(fmaf(acc[0], sc_l2e, base));
      z1 += __builtin_amdgcn_exp2f(fmaf(acc[1], sc_l2e, base + sl_l2e));
      z2 += __builtin_amdgcn_exp2f(fmaf(acc[2], sc_l2e, base + 2.f * sl_l2e));
      z3 += __builtin_amdgcn_exp2f(fmaf(acc[3], sc_l2e, base + 3.f * sl_l2e));
    }
    __syncthreads();
  }
  float z = (z0 + z1) + (z2 + z3);
  z += __shfl_xor(z, 16, 64);
  z += __shfl_xor(z, 32, 64);
  const float minv = 1.0f / z;

  // ===== Pass B =====
  f32x4 oacc[4];
#pragma unroll
  for (int et = 0; et < 4; ++et) oacc[et] = (f32x4){0.f, 0.f, 0.f, 0.f};

  float* Pb =
      Pout + ((size_t)(b * H_ + h) * L_ + q0 + 16 * w + col) * L_ + 4 * kg;

  STAGE_K(0, 0);
  STAGE_V(0, 0);
  __syncthreads();
  for (int c = 0; c < NCH; ++c) {
    if (c + 1 < NCH) {
      STAGE_K(c + 1, (c + 1) & 1);
      STAGE_V(c + 1, (c + 1) & 1);
    }
    const unsigned short* kb = sK[c & 1];
    const unsigned short* vb = sVT[c & 1];
#pragma unroll
    for (int kt = 0; kt < 4; ++kt) {
      const int row = 16 * kt + col;
      short8 k0 = *reinterpret_cast<const short8*>(
          &kb[row * 64 + ((kg ^ (row & 7)) << 3)]);
      short8 k1 = *reinterpret_cast<const short8*>(
          &kb[row * 64 + (((kg + 4) ^ (row & 7)) << 3)]);
      f32x4 acc = {0.f, 0.f, 0.f, 0.f};
      acc = __builtin_amdgcn_mfma_f32_16x16x32_bf16(k0, qf0, acc, 0, 0, 0);
      acc = __builtin_amdgcn_mfma_f32_16x16x32_bf16(k1, qf1, acc, 0, 0, 0);
      // V^T fragments from LDS: e = 16et+col, s-block g0 = 2kt + (kg>>1)
      short4v vf[4];
      const int g0 = 2 * kt + (kg >> 1);
      const int so = 4 * (kg & 1);
#pragma unroll
      for (int et = 0; et < 4; ++et) {
        const int e = 16 * et + col;
        vf[et] = *reinterpret_cast<const short4v*>(
            &vb[e * 64 + ((g0 ^ (e & 7)) << 3) + so]);
      }
      const float base = fmaf((float)(CHUNK * c + 16 * kt), sl_l2e, kbias0);
      f32x4 pf;
      pf[0] = __builtin_amdgcn_exp2f(fmaf(acc[0], sc_l2e, base)) * minv;
      pf[1] =
          __builtin_amdgcn_exp2f(fmaf(acc[1], sc_l2e, base + sl_l2e)) * minv;
      pf[2] = __builtin_amdgcn_exp2f(fmaf(acc[2], sc_l2e, base + 2.f * sl_l2e)) *
              minv;
      pf[3] = __builtin_amdgcn_exp2f(fmaf(acc[3], sc_l2e, base + 3.f * sl_l2e)) *
              minv;
      // P store straight from D-frag (16 rows x 64B per instruction)
      *reinterpret_cast<f32x4*>(Pb + CHUNK * c + 16 * kt) = pf;
      // pack to bf16 A-frag (k = 4*kg + j == this lane's keys) and PV
      short4v pa = {(short)f2bf(pf[0]), (short)f2bf(pf[1]), (short)f2bf(pf[2]),
                    (short)f2bf(pf[3])};
#pragma unroll
      for (int et = 0; et < 4; ++et) oacc[et] = mfma16(pa, vf[et], oacc[et]);
    }
    __syncthreads();
  }

  // ---- write O: q = q0+16w+4kg+r, e = 16et+col ----
  float* Vo = Vout + (((size_t)b * L_ + q0 + 16 * w) * H_ + h) * E_;
#pragma unroll
  for (int et = 0; et < 4; ++et) {
#pragma unroll
    for (int r = 0; r < 4; ++r) {
      __builtin_nontemporal_store(oacc[et][r],
                                  &Vo[(4 * kg + r) * RSTRIDE + 16 * et + col]);
    }
  }
}

extern "C" void kernel_launch(void* const* d_in, const int* in_sizes, int n_in,
                              void* d_out, int out_size, void* d_ws,
                              size_t ws_size, hipStream_t stream) {
  const float* Q = (const float*)d_in[0];
  const float* K = (const float*)d_in[1];
  const float* V = (const float*)d_in[2];
  float* out = (float*)d_out;
  float* Vo = out;                              // [B,L,H,E]
  float* Po = out + (size_t)B_ * L_ * H_ * E_;  // [B,H,L,L]
  unsigned short* Kbf = (unsigned short*)d_ws;  // 8 MB
  unsigned short* VTbf = Kbf + (size_t)B_ * H_ * L_ * E_;  // 8 MB
  hipLaunchKernelGGL(prep_kv, dim3(NCH * B_ * H_), dim3(256), 0, stream, K, V,
                     Kbf, VTbf);
  hipLaunchKernelGGL(alibi_attn, dim3((L_ / QBLK) * H_ * B_), dim3(256), 0,
                     stream, Q, Kbf, VTbf, Vo, Po);
}

// Round 12
// 95.359 us; speedup vs baseline: 1.2766x; 1.1062x over previous
//
#include <hip/hip_runtime.h>
#include <hip/hip_bf16.h>

// ALiBi attention, B=8 L=1024 H=8 E=64, fp32 in/out, bf16 MFMA inside.
// Outputs: V [B,L,H,E] then series [B,H,L,L] concatenated in d_out.
// R12 = R11 (counted-vmcnt pipelined staging) with the races sealed:
//  - sched_barrier(0) pins every STAGE's global_load_lds group ahead of the
//    iteration's P-stores, so vmcnt counts match program order (m152 rule);
//  - pass-A epilogue drops to vmcnt(0) when no prefetch is in flight.
// Geometry: CHUNK=64, 4 waves x 16 q-rows, grid 1024, 32KB LDS, 4 blk/CU.
// Scratch: bf16 K and V^T chunks pre-swizzled in gload-linear order.

typedef short short8 __attribute__((ext_vector_type(8)));
typedef short short4v __attribute__((ext_vector_type(4)));
typedef float f32x4 __attribute__((ext_vector_type(4)));
typedef unsigned short u16x4 __attribute__((ext_vector_type(4)));

#define B_ 8
#define L_ 1024
#define H_ 8
#define E_ 64
#define RSTRIDE (H_ * E_)       // 512 floats between seq rows
#define QBLK 64                 // 4 waves x 16 q-rows
#define CHUNK 64                // keys per chunk
#define NCH (L_ / CHUNK)        // 16
#define CHUNK_USH (CHUNK * E_)  // 4096 ushorts = 8KB per chunk tile

__device__ __forceinline__ unsigned short f2bf(float f) {
  return __builtin_bit_cast(unsigned short, __float2bfloat16(f));
}
__device__ __forceinline__ short8 ldfrag(const float* p) {
  float4 a = *reinterpret_cast<const float4*>(p);
  float4 b = *reinterpret_cast<const float4*>(p + 4);
  return (short8){(short)f2bf(a.x), (short)f2bf(a.y), (short)f2bf(a.z),
                  (short)f2bf(a.w), (short)f2bf(b.x), (short)f2bf(b.y),
                  (short)f2bf(b.z), (short)f2bf(b.w)};
}

__device__ __forceinline__ f32x4 mfma16(short4v a, short4v b, f32x4 c) {
#if __has_builtin(__builtin_amdgcn_mfma_f32_16x16x16bf16_1k)
  return __builtin_amdgcn_mfma_f32_16x16x16bf16_1k(a, b, c, 0, 0, 0);
#else
  asm volatile(
      "s_nop 1\n\t"
      "v_mfma_f32_16x16x16_bf16 %0, %1, %2, %0\n\t"
      "s_nop 2"
      : "+v"(c)
      : "v"(a), "v"(b));
  return c;
#endif
}

__device__ __forceinline__ void gld16(const unsigned short* g,
                                      unsigned short* l) {
  __builtin_amdgcn_global_load_lds(
      (const __attribute__((address_space(1))) unsigned int*)g,
      (__attribute__((address_space(3))) unsigned int*)l, 16, 0, 0);
}

// counted-vmcnt barrier: the N newest VMEM ops may stay in flight
#define BAR_VM(N)                                         \
  {                                                       \
    asm volatile("s_waitcnt vmcnt(" #N ")" ::: "memory"); \
    __builtin_amdgcn_s_barrier();                         \
    __builtin_amdgcn_sched_barrier(0);                    \
  }

// ---- prep: scratch in gload-linear swizzled block order ----
// K chunk (64 s x 64 e): 16B-block j <-> (s = j>>3, e8 = (j&7)^(s&7)).
// VT chunk (64 e x 64 s): block j <-> (e = j>>3, g = (j&7)^(e&7)).
__global__ __launch_bounds__(256, 4) void prep_kv(
    const float* __restrict__ Kg, const float* __restrict__ Vg,
    unsigned short* __restrict__ Kbf, unsigned short* __restrict__ VTbf) {
  __shared__ unsigned short vt[64 * 64];  // V^T tile in swizzled space

  const int t = threadIdx.x;
  const int id = blockIdx.x;
  const int bh = id & 63;  // id%8 = h -> same XCD as consumers
  const int sc = id >> 6;  // chunk 0..15
  const int h = bh & 7, b = bh >> 3;
  const int s0 = sc * CHUNK;

  const float* Kb = Kg + ((size_t)b * L_ + s0) * RSTRIDE + h * E_;
  const float* Vb = Vg + ((size_t)b * L_ + s0) * RSTRIDE + h * E_;
  unsigned short* Ko = Kbf + (size_t)(bh * NCH + sc) * CHUNK_USH;
  unsigned short* Vo = VTbf + (size_t)(bh * NCH + sc) * CHUNK_USH;

  // K: direct convert into swizzled block order (reads stay coalesced)
#pragma unroll
  for (int i = 0; i < 2; ++i) {
    const int j = t + 256 * i;  // 512 blocks
    const int s = j >> 3;
    const int e8 = (j & 7) ^ (s & 7);
    const float* kp = Kb + (size_t)s * RSTRIDE + 8 * e8;
    float4 a = *reinterpret_cast<const float4*>(kp);
    float4 c = *reinterpret_cast<const float4*>(kp + 4);
    *reinterpret_cast<u16x4*>(&Ko[j * 8]) =
        (u16x4){f2bf(a.x), f2bf(a.y), f2bf(a.z), f2bf(a.w)};
    *reinterpret_cast<u16x4*>(&Ko[j * 8 + 4]) =
        (u16x4){f2bf(c.x), f2bf(c.y), f2bf(c.z), f2bf(c.w)};
  }
  // V: transpose through LDS (swizzled space), then linear copy out
  {
    const int e = t & 63, w = t >> 6;
#pragma unroll
    for (int i = 0; i < 4; ++i) {
      const int s4 = 4 * w + 16 * i;
      const float* vp = Vb + (size_t)s4 * RSTRIDE + e;
      u16x4 u = {f2bf(vp[0]), f2bf(vp[RSTRIDE]), f2bf(vp[2 * RSTRIDE]),
                 f2bf(vp[3 * RSTRIDE])};
      *reinterpret_cast<u16x4*>(
          &vt[e * 64 + (((s4 >> 3) ^ (e & 7)) << 3) + (s4 & 7)]) = u;
    }
  }
  __syncthreads();
#pragma unroll
  for (int i = 0; i < 2; ++i) {
    const int j = t + 256 * i;  // swizzled space is already block-linear
    u16x4 u0 = *reinterpret_cast<const u16x4*>(&vt[j * 8]);
    u16x4 u1 = *reinterpret_cast<const u16x4*>(&vt[j * 8 + 4]);
    *reinterpret_cast<u16x4*>(&Vo[j * 8]) = u0;
    *reinterpret_cast<u16x4*>(&Vo[j * 8 + 4]) = u1;
  }
}

// ---- main: 4 waves x 16 q-rows, counted-vmcnt pipelined staging ----
__global__ __launch_bounds__(256, 4) void alibi_attn(
    const float* __restrict__ Qg, const unsigned short* __restrict__ Kbf,
    const unsigned short* __restrict__ VTbf, float* __restrict__ Vout,
    float* __restrict__ Pout) {
  // 32KB union: pass A = 4 K-buffers; pass B = K in [0],[1], VT in [2],[3]
  __shared__ unsigned short sBuf[4][CHUNK_USH];

  const int t = threadIdx.x;
  const int lane = t & 63;
  const int w = t >> 6;
  const int col = lane & 15;
  const int kg = lane >> 4;

  const int id = blockIdx.x;  // id%8 = h -> XCD-pinned scratch in L2
  const int qb = id >> 6;
  const int bh = id & 63;
  const int h = bh & 7;
  const int b = bh >> 3;
  const int q0 = qb * QBLK;

  const float sc_l2e = 0.125f * 1.44269504f;
  const float sl_l2e = exp2f(-(float)(h + 1) * 0.125f) * 1.44269504f;

  const unsigned short* Kc = Kbf + (size_t)bh * NCH * CHUNK_USH;
  const unsigned short* Vc = VTbf + (size_t)bh * NCH * CHUNK_USH;

  // Q B-fragments: q-row = col, k = 8*kg + j (+32 for second slice)
  short8 qf0, qf1;
  {
    const float* qp =
        Qg + ((size_t)b * L_ + q0 + 16 * w + col) * RSTRIDE + h * E_ + 8 * kg;
    qf0 = ldfrag(qp);
    qf1 = ldfrag(qp + 32);
  }

  const float kbias0 = sl_l2e * (float)(4 * kg - 1023) - 32.0f;

  // stage one 8KB chunk: 2 x gld16 per thread (segs w, w+4), then PIN the
  // issue point so later stores cannot be scheduled ahead of these loads.
#define STAGE(srcbase, c, dst)                                       \
  {                                                                  \
    const unsigned short* src = (srcbase) + (size_t)(c)*CHUNK_USH;   \
    _Pragma("unroll") for (int i = 0; i < 2; ++i) {                  \
      const int seg = i * 4 + w;                                     \
      gld16(src + (size_t)(seg * 64 + lane) * 8, (dst) + seg * 512); \
    }                                                                \
  }
#define PIN() __builtin_amdgcn_sched_barrier(0)

  // ===== Pass A: z = sum exp2(u-32); 4 bufs, depth-2 prefetch =====
  float z0 = 0.f, z1 = 0.f, z2 = 0.f, z3 = 0.f;
  STAGE(Kc, 0, sBuf[0]);
  STAGE(Kc, 1, sBuf[1]);
  PIN();
  BAR_VM(2);  // chunk 0 landed; chunk 1 in flight
  for (int c = 0; c < NCH; ++c) {
    if (c + 2 < NCH) {
      STAGE(Kc, c + 2, sBuf[(c + 2) & 3]);
      PIN();
    }
    const unsigned short* kb = sBuf[c & 3];
#pragma unroll
    for (int kt = 0; kt < 4; ++kt) {
      const int row = 16 * kt + col;
      short8 k0 = *reinterpret_cast<const short8*>(
          &kb[row * 64 + ((kg ^ (row & 7)) << 3)]);
      short8 k1 = *reinterpret_cast<const short8*>(
          &kb[row * 64 + (((kg + 4) ^ (row & 7)) << 3)]);
      f32x4 acc = {0.f, 0.f, 0.f, 0.f};
      acc = __builtin_amdgcn_mfma_f32_16x16x32_bf16(k0, qf0, acc, 0, 0, 0);
      acc = __builtin_amdgcn_mfma_f32_16x16x32_bf16(k1, qf1, acc, 0, 0, 0);
      const float base = fmaf((float)(CHUNK * c + 16 * kt), sl_l2e, kbias0);
      z0 += __builtin_amdgcn_exp2f(fmaf(acc[0], sc_l2e, base));
      z1 += __builtin_amdgcn_exp2f(fmaf(acc[1], sc_l2e, base + sl_l2e));
      z2 += __builtin_amdgcn_exp2f(fmaf(acc[2], sc_l2e, base + 2.f * sl_l2e));
      z3 += __builtin_amdgcn_exp2f(fmaf(acc[3], sc_l2e, base + 3.f * sl_l2e));
    }
    // need chunk c+1 landed. While the prefetch stream runs, the 2 newest
    // in-flight loads are chunk c+2's -> vmcnt(2). Once the stream dries up
    // (c+2 >= NCH) nothing newer is in flight -> full drain vmcnt(0).
    if (c + 2 < NCH) {
      BAR_VM(2);
    } else {
      BAR_VM(0);
    }
  }
  float z = (z0 + z1) + (z2 + z3);
  z += __shfl_xor(z, 16, 64);
  z += __shfl_xor(z, 32, 64);
  const float minv = 1.0f / z;

  // ===== Pass B: 2K+2V buffers, issue-4 / vmcnt(4) =====
  f32x4 oacc[4];
#pragma unroll
  for (int et = 0; et < 4; ++et) oacc[et] = (f32x4){0.f, 0.f, 0.f, 0.f};

  float* Pb =
      Pout + ((size_t)(b * H_ + h) * L_ + q0 + 16 * w + col) * L_ + 4 * kg;

  __syncthreads();  // pass A fully done before buffer repurposing
  STAGE(Kc, 0, sBuf[0]);
  STAGE(Vc, 0, sBuf[2]);
  PIN();
  BAR_VM(0);
  for (int c = 0; c < NCH; ++c) {
    if (c + 1 < NCH) {
      STAGE(Kc, c + 1, sBuf[(c + 1) & 1]);
      STAGE(Vc, c + 1, sBuf[2 + ((c + 1) & 1)]);
      PIN();  // pin the 4 loads ahead of this iteration's 4 P-stores
    }
    const unsigned short* kb = sBuf[c & 1];
    const unsigned short* vb = sBuf[2 + (c & 1)];
#pragma unroll
    for (int kt = 0; kt < 4; ++kt) {
      const int row = 16 * kt + col;
      short8 k0 = *reinterpret_cast<const short8*>(
          &kb[row * 64 + ((kg ^ (row & 7)) << 3)]);
      short8 k1 = *reinterpret_cast<const short8*>(
          &kb[row * 64 + (((kg + 4) ^ (row & 7)) << 3)]);
      f32x4 acc = {0.f, 0.f, 0.f, 0.f};
      acc = __builtin_amdgcn_mfma_f32_16x16x32_bf16(k0, qf0, acc, 0, 0, 0);
      acc = __builtin_amdgcn_mfma_f32_16x16x32_bf16(k1, qf1, acc, 0, 0, 0);
      // V^T fragments from LDS: e = 16et+col, s-block g0 = 2kt + (kg>>1)
      short4v vf[4];
      const int g0 = 2 * kt + (kg >> 1);
      const int so = 4 * (kg & 1);
#pragma unroll
      for (int et = 0; et < 4; ++et) {
        const int e = 16 * et + col;
        vf[et] = *reinterpret_cast<const short4v*>(
            &vb[e * 64 + ((g0 ^ (e & 7)) << 3) + so]);
      }
      const float base = fmaf((float)(CHUNK * c + 16 * kt), sl_l2e, kbias0);
      f32x4 pf;
      pf[0] = __builtin_amdgcn_exp2f(fmaf(acc[0], sc_l2e, base)) * minv;
      pf[1] =
          __builtin_amdgcn_exp2f(fmaf(acc[1], sc_l2e, base + sl_l2e)) * minv;
      pf[2] = __builtin_amdgcn_exp2f(fmaf(acc[2], sc_l2e, base + 2.f * sl_l2e)) *
              minv;
      pf[3] = __builtin_amdgcn_exp2f(fmaf(acc[3], sc_l2e, base + 3.f * sl_l2e)) *
              minv;
      // P store straight from D-frag (stays in flight across the barrier)
      *reinterpret_cast<f32x4*>(Pb + CHUNK * c + 16 * kt) = pf;
      // pack to bf16 A-frag (k = 4*kg + j == this lane's keys) and PV
      short4v pa = {(short)f2bf(pf[0]), (short)f2bf(pf[1]), (short)f2bf(pf[2]),
                    (short)f2bf(pf[3])};
#pragma unroll
      for (int et = 0; et < 4; ++et) oacc[et] = mfma16(pa, vf[et], oacc[et]);
    }
    // program order per iter (pinned): [4 stage loads][4 P-stores].
    // vmcnt(4): waits for the loads (and all older ops), leaves only the
    // 4 newest (this iter's stores) in flight. Last iter (no stage): the
    // 4 in flight are stores -> no wait needed, none taken.
    BAR_VM(4);
  }

  // ---- write O: q = q0+16w+4kg+r, e = 16et+col ----
  float* Vo = Vout + (((size_t)b * L_ + q0 + 16 * w) * H_ + h) * E_;
#pragma unroll
  for (int et = 0; et < 4; ++et) {
#pragma unroll
    for (int r = 0; r < 4; ++r) {
      __builtin_nontemporal_store(oacc[et][r],
                                  &Vo[(4 * kg + r) * RSTRIDE + 16 * et + col]);
    }
  }
}

extern "C" void kernel_launch(void* const* d_in, const int* in_sizes, int n_in,
                              void* d_out, int out_size, void* d_ws,
                              size_t ws_size, hipStream_t stream) {
  const float* Q = (const float*)d_in[0];
  const float* K = (const float*)d_in[1];
  const float* V = (const float*)d_in[2];
  float* out = (float*)d_out;
  float* Vo = out;                              // [B,L,H,E]
  float* Po = out + (size_t)B_ * L_ * H_ * E_;  // [B,H,L,L]
  unsigned short* Kbf = (unsigned short*)d_ws;  // 8 MB
  unsigned short* VTbf = Kbf + (size_t)B_ * H_ * L_ * E_;  // 8 MB
  hipLaunchKernelGGL(prep_kv, dim3(NCH * B_ * H_), dim3(256), 0, stream, K, V,
                     Kbf, VTbf);
  hipLaunchKernelGGL(alibi_attn, dim3((L_ / QBLK) * H_ * B_), dim3(256), 0,
                     stream, Q, Kbf, VTbf, Vo, Po);
}